// Round 2
// baseline (399.687 us; speedup 1.0000x reference)
//
#include <hip/hip_runtime.h>

#define NN   8192
#define FIN  512
#define FOUT 64
#define KHALF 4096

typedef __attribute__((ext_vector_type(8)))  short short8;
typedef __attribute__((ext_vector_type(4)))  float floatx4;
typedef __attribute__((ext_vector_type(16))) float floatx16;

__device__ __forceinline__ unsigned f2bf_u(float f) {
  union { float f; unsigned u; } v; v.f = f;
  return (v.u + 0x7fffu + ((v.u >> 16) & 1u)) >> 16;  // RTNE bf16
}
__device__ __forceinline__ unsigned pack2(float a, float b) {
  return f2bf_u(a) | (f2bf_u(b) << 16);
}
__device__ __forceinline__ short8 as_s8(int4 v) {
  union { int4 a; short8 b; } u; u.a = v; return u.b;
}

// ---------------- Kernel 1: h = inp @ W (bf16 MFMA, fp32 accum) -------------
// Writes hT (bf16 [64][8192] f-major), f1, f2 (fp32). Validated round 1.
__global__ __launch_bounds__(256) void k1_gemm_h(
    const float* __restrict__ inp, const float* __restrict__ W,
    const float* __restrict__ a,
    float* __restrict__ f1, float* __restrict__ f2,
    unsigned short* __restrict__ hT)
{
  __shared__ unsigned short at[32][72];
  __shared__ unsigned short wt[64][72];
  __shared__ float hsm[32][65];
  __shared__ float alds[2 * FOUT];

  const int tid   = threadIdx.x;
  const int rbase = blockIdx.x * 32;
  if (tid < 2 * FOUT) alds[tid] = a[tid];

  const int lane = tid & 63;
  const int wv   = tid >> 6;
  const int l15  = lane & 15;
  const int q    = lane >> 4;
  const int mi   = wv & 1;
  const int ni0  = (wv >> 1) * 2;

  const int r_a  = tid >> 3;
  const int k8   = (tid & 7) * 8;
  const int n_w  = tid & 63;
  const int kb_w = (tid >> 6) * 16;

  floatx4 acc0 = {0.f, 0.f, 0.f, 0.f};
  floatx4 acc1 = {0.f, 0.f, 0.f, 0.f};

  for (int kk0 = 0; kk0 < FIN; kk0 += 64) {
    __syncthreads();
    const float* ap = inp + (rbase + r_a) * FIN + kk0 + k8;
    float4 v0 = *(const float4*)ap;
    float4 v1 = *(const float4*)(ap + 4);
    *(uint4*)&at[r_a][k8] = make_uint4(pack2(v0.x, v0.y), pack2(v0.z, v0.w),
                                       pack2(v1.x, v1.y), pack2(v1.z, v1.w));
#pragma unroll
    for (int kk2 = 0; kk2 < 16; ++kk2)
      wt[n_w][kb_w + kk2] = (unsigned short)f2bf_u(W[(kk0 + kb_w + kk2) * FOUT + n_w]);
    __syncthreads();
#pragma unroll
    for (int ks = 0; ks < 2; ++ks) {
      short8 af = *(const short8*)&at[mi * 16 + l15][ks * 32 + q * 8];
      short8 b0 = *(const short8*)&wt[ni0 * 16 + l15][ks * 32 + q * 8];
      short8 b1 = *(const short8*)&wt[(ni0 + 1) * 16 + l15][ks * 32 + q * 8];
      acc0 = __builtin_amdgcn_mfma_f32_16x16x32_bf16(af, b0, acc0, 0, 0, 0);
      acc1 = __builtin_amdgcn_mfma_f32_16x16x32_bf16(af, b1, acc1, 0, 0, 0);
    }
  }

  {
    const int m0 = mi * 16 + q * 4;
    const int i0 = rbase + m0;
    {
      const int n = ni0 * 16 + l15;
#pragma unroll
      for (int rg = 0; rg < 4; ++rg) hsm[m0 + rg][n] = acc0[rg];
      *(uint2*)&hT[n * NN + i0] = make_uint2(pack2(acc0[0], acc0[1]),
                                             pack2(acc0[2], acc0[3]));
    }
    {
      const int n = (ni0 + 1) * 16 + l15;
#pragma unroll
      for (int rg = 0; rg < 4; ++rg) hsm[m0 + rg][n] = acc1[rg];
      *(uint2*)&hT[n * NN + i0] = make_uint2(pack2(acc1[0], acc1[1]),
                                             pack2(acc1[2], acc1[3]));
    }
  }
  __syncthreads();
  if (tid < 32) {
    float s1 = 0.f, s2 = 0.f;
#pragma unroll 8
    for (int c = 0; c < FOUT; ++c) {
      float hv = hsm[tid][c];
      s1 += hv * alds[c];
      s2 += hv * alds[FOUT + c];
    }
    f1[rbase + tid] = s1;
    f2[rbase + tid] = s2;
  }
}

// ---------------- Kernel 2: barrier-free fused attention partials -----------
// outT = hT . wT via mfma_f32_32x32x16_bf16. Each lane computes its own
// B-fragment (8 contiguous w[i][j]) from adj/f2 register loads; A-fragment is
// a contiguous 16B load from L2-resident hT. NO LDS, NO barriers in the
// K-loop. 4 waves split K within the block; K additionally split 2x across
// blocks. Partial (un-normalized) sums + row-weight sums written to ws.
__device__ __forceinline__ short8 mkw(const int4 A0, const int4 A1,
                                      const float4 F0, const float4 F1,
                                      const float f1v, float& lsum) {
  float e, w0, w1, w2, w3, w4, w5, w6, w7;
  e = f1v + F0.x; e = fmaxf(e, 0.2f * e); w0 = A0.x ? __expf(e) : 0.f;
  e = f1v + F0.y; e = fmaxf(e, 0.2f * e); w1 = A0.y ? __expf(e) : 0.f;
  e = f1v + F0.z; e = fmaxf(e, 0.2f * e); w2 = A0.z ? __expf(e) : 0.f;
  e = f1v + F0.w; e = fmaxf(e, 0.2f * e); w3 = A0.w ? __expf(e) : 0.f;
  e = f1v + F1.x; e = fmaxf(e, 0.2f * e); w4 = A1.x ? __expf(e) : 0.f;
  e = f1v + F1.y; e = fmaxf(e, 0.2f * e); w5 = A1.y ? __expf(e) : 0.f;
  e = f1v + F1.z; e = fmaxf(e, 0.2f * e); w6 = A1.z ? __expf(e) : 0.f;
  e = f1v + F1.w; e = fmaxf(e, 0.2f * e); w7 = A1.w ? __expf(e) : 0.f;
  lsum += ((w0 + w1) + (w2 + w3)) + ((w4 + w5) + (w6 + w7));
  uint4 u = make_uint4(pack2(w0, w1), pack2(w2, w3), pack2(w4, w5), pack2(w6, w7));
  union { uint4 a; short8 b; } c; c.a = u; return c.b;
}

__global__ __launch_bounds__(256, 2) void k2_attn(
    const int* __restrict__ adj,
    const float* __restrict__ f1g, const float* __restrict__ f2g,
    const unsigned short* __restrict__ hT,
    float* __restrict__ part, float* __restrict__ lpart)
{
  __shared__ float pbuf[4][2048];   // [wave][i32*64 + f]
  __shared__ float lsw[4][32];

  const int tid   = threadIdx.x;
  const int wv    = tid >> 6;
  const int lane  = tid & 63;
  const int i32   = lane & 31;
  const int hi    = lane >> 5;
  const int rbase = (blockIdx.x >> 1) * 32;
  const int kh    = blockIdx.x & 1;
  const int kbase = kh * KHALF + wv * 32 + hi * 8;

  const int*            ap  = adj + (size_t)(rbase + i32) * NN + kbase;
  const float*          fp  = f2g + kbase;
  const unsigned short* h0p = hT + (size_t)i32 * NN + kbase;
  const unsigned short* h1p = h0p + (size_t)32 * NN;
  const float f1v = f1g[rbase + i32];

  floatx16 acc0 = {0,0,0,0,0,0,0,0,0,0,0,0,0,0,0,0};
  floatx16 acc1 = {0,0,0,0,0,0,0,0,0,0,0,0,0,0,0,0};
  float lsum = 0.f;

  // 1-deep register prefetch; no barriers -> fine-grained vmcnt pipelining
  int4  A0  = *(const int4*)(ap);       int4  A1  = *(const int4*)(ap + 4);
  int4  A2  = *(const int4*)(ap + 16);  int4  A3  = *(const int4*)(ap + 20);
  float4 F0 = *(const float4*)(fp);     float4 F1 = *(const float4*)(fp + 4);
  float4 F2 = *(const float4*)(fp + 16);float4 F3 = *(const float4*)(fp + 20);
  int4  H00 = *(const int4*)(h0p);      int4  H01 = *(const int4*)(h0p + 16);
  int4  H10 = *(const int4*)(h1p);      int4  H11 = *(const int4*)(h1p + 16);

  for (int it = 0; it < KHALF / 128; ++it) {
    const int nk = (it < KHALF / 128 - 1) ? (it + 1) * 128 : 0;  // safe dummy on last
    int4  nA0 = *(const int4*)(ap + nk);       int4  nA1 = *(const int4*)(ap + nk + 4);
    int4  nA2 = *(const int4*)(ap + nk + 16);  int4  nA3 = *(const int4*)(ap + nk + 20);
    float4 nF0 = *(const float4*)(fp + nk);    float4 nF1 = *(const float4*)(fp + nk + 4);
    float4 nF2 = *(const float4*)(fp + nk + 16);float4 nF3 = *(const float4*)(fp + nk + 20);
    int4  nH00 = *(const int4*)(h0p + nk);     int4  nH01 = *(const int4*)(h0p + nk + 16);
    int4  nH10 = *(const int4*)(h1p + nk);     int4  nH11 = *(const int4*)(h1p + nk + 16);

    short8 b0 = mkw(A0, A1, F0, F1, f1v, lsum);
    acc0 = __builtin_amdgcn_mfma_f32_32x32x16_bf16(as_s8(H00), b0, acc0, 0, 0, 0);
    acc1 = __builtin_amdgcn_mfma_f32_32x32x16_bf16(as_s8(H10), b0, acc1, 0, 0, 0);
    short8 b1 = mkw(A2, A3, F2, F3, f1v, lsum);
    acc0 = __builtin_amdgcn_mfma_f32_32x32x16_bf16(as_s8(H01), b1, acc0, 0, 0, 0);
    acc1 = __builtin_amdgcn_mfma_f32_32x32x16_bf16(as_s8(H11), b1, acc1, 0, 0, 0);

    A0 = nA0; A1 = nA1; A2 = nA2; A3 = nA3;
    F0 = nF0; F1 = nF1; F2 = nF2; F3 = nF3;
    H00 = nH00; H01 = nH01; H10 = nH10; H11 = nH11;
  }

  // combine wave lsum partials: lanes (i32, i32+32) hold the two j-subsets
  lsum += __shfl_xor(lsum, 32, 64);
  if (lane < 32) lsw[wv][i32] = lsum;

  // stash per-wave acc partials (C/D layout: col=lane&31, row=(rg&3)+8*(rg>>2)+4*hi)
#pragma unroll
  for (int rg = 0; rg < 16; ++rg) {
    const int m = (rg & 3) + 8 * (rg >> 2) + 4 * hi;
    pbuf[wv][i32 * 64 + m]      = acc0[rg];
    pbuf[wv][i32 * 64 + 32 + m] = acc1[rg];
  }
  __syncthreads();

  // cross-wave reduce + coalesced store of partials
  const int e0 = tid * 8;            // 2048 elems / 256 thr
  const int irow = rbase + (e0 >> 6);
  const int f0c  = e0 & 63;
  float* dst = part + ((size_t)kh * NN + irow) * 64 + f0c;
#pragma unroll
  for (int c = 0; c < 2; ++c) {
    float4 s = *(const float4*)&pbuf[0][e0 + c * 4];
    float4 s1 = *(const float4*)&pbuf[1][e0 + c * 4];
    float4 s2 = *(const float4*)&pbuf[2][e0 + c * 4];
    float4 s3 = *(const float4*)&pbuf[3][e0 + c * 4];
    s.x += s1.x + s2.x + s3.x; s.y += s1.y + s2.y + s3.y;
    s.z += s1.z + s2.z + s3.z; s.w += s1.w + s2.w + s3.w;
    *(float4*)(dst + c * 4) = s;
  }
  if (tid < 32)
    lpart[(size_t)kh * NN + rbase + tid] =
        lsw[0][tid] + lsw[1][tid] + lsw[2][tid] + lsw[3][tid];
}

// ---------------- Kernel 3: combine k-halves, normalize, ELU ----------------
__global__ __launch_bounds__(256) void k3_combine(
    const float* __restrict__ part, const float* __restrict__ lpart,
    float* __restrict__ out)
{
  const int gid = blockIdx.x * 256 + threadIdx.x;   // 131072 float4s
  const int i = gid >> 4;
  const int c = (gid & 15) * 4;
  const float inv = 1.f / (lpart[i] + lpart[NN + i]);
  float4 p0 = *(const float4*)(part + (size_t)i * 64 + c);
  float4 p1 = *(const float4*)(part + ((size_t)NN + i) * 64 + c);
  float4 v;
  v.x = (p0.x + p1.x) * inv; v.x = (v.x > 0.f) ? v.x : (__expf(v.x) - 1.f);
  v.y = (p0.y + p1.y) * inv; v.y = (v.y > 0.f) ? v.y : (__expf(v.y) - 1.f);
  v.z = (p0.z + p1.z) * inv; v.z = (v.z > 0.f) ? v.z : (__expf(v.z) - 1.f);
  v.w = (p0.w + p1.w) * inv; v.w = (v.w > 0.f) ? v.w : (__expf(v.w) - 1.f);
  *(float4*)(out + (size_t)i * 64 + c) = v;
}

extern "C" void kernel_launch(void* const* d_in, const int* in_sizes, int n_in,
                              void* d_out, int out_size, void* d_ws, size_t ws_size,
                              hipStream_t stream) {
  (void)in_sizes; (void)n_in; (void)out_size; (void)ws_size;
  const float* inp = (const float*)d_in[0];
  const int*   adj = (const int*)d_in[1];
  const float* W   = (const float*)d_in[2];
  const float* a   = (const float*)d_in[3];
  float* out = (float*)d_out;

  float* f1 = (float*)d_ws;                         // 8192
  float* f2 = f1 + NN;                              // 8192
  unsigned short* hT = (unsigned short*)(f2 + NN);  // 64*8192 bf16 = 1 MB
  float* part  = (float*)(hT + (size_t)FOUT * NN);  // 2*8192*64 = 4 MB
  float* lpart = part + 2 * (size_t)NN * FOUT;      // 2*8192

  k1_gemm_h<<<NN / 32, 256, 0, stream>>>(inp, W, a, f1, f2, hT);
  k2_attn<<<(NN / 32) * 2, 256, 0, stream>>>(adj, f1, f2, hT, part, lpart);
  k3_combine<<<NN * FOUT / 4 / 256, 256, 0, stream>>>(part, lpart, out);
}